// Round 2
// baseline (304.144 us; speedup 1.0000x reference)
//
#include <hip/hip_runtime.h>

// BNB 8-bit embedding dequant-gather:
//   out[t, :] = (float)q_weight[x[t], :] * (absmax[x[t]] / 127)
// B*S = 32768 tokens, DIM = 1024, VOCAB = 50257.
//
// NOTE: harness widens ALL integer inputs to int32 — q_weight arrives as
// int32 per element (NOT packed int8 bytes). Round-1 failure (absmax 7.9,
// worse than zeros) was from unpacking bytes of widened int32s.
//
// Memory-bound: 128 MiB int32 gathered reads + 128 MiB fp32 writes.
// Layout: 1 block = 1 token, 256 threads; lane i handles elems [4i, 4i+4):
//   - 16B int4 load per lane (4 KiB contiguous per block)
//   - 16B float4 store per lane (4 KiB contiguous per block)

__global__ __launch_bounds__(256) void bnb8_embed_kernel(
    const int* __restrict__ x,
    const int* __restrict__ qw,      // widened int8 values, one int32 each
    const float* __restrict__ absmax,
    float* __restrict__ out,
    int dim)
{
    const int t = blockIdx.x;                 // token index (block-uniform)
    const int row = x[t];                     // uniform -> scalar load
    const float scale = absmax[row] * (1.0f / 127.0f);

    const int i = threadIdx.x << 2;           // element offset within row
    const size_t row_off = (size_t)row * (size_t)dim + i;
    const size_t out_off = (size_t)t * (size_t)dim + i;

    const int4 q = *(const int4*)(qw + row_off);

    float4 o;
    o.x = (float)q.x * scale;
    o.y = (float)q.y * scale;
    o.z = (float)q.z * scale;
    o.w = (float)q.w * scale;

    *(float4*)(out + out_off) = o;
}

extern "C" void kernel_launch(void* const* d_in, const int* in_sizes, int n_in,
                              void* d_out, int out_size, void* d_ws, size_t ws_size,
                              hipStream_t stream) {
    const int*   x      = (const int*)d_in[0];    // [B*S] int32
    const int*   qw     = (const int*)d_in[1];    // [VOCAB*DIM] int32 (widened int8)
    const float* absmax = (const float*)d_in[2];  // [VOCAB] f32
    float*       out    = (float*)d_out;          // [B*S*DIM] f32

    const int n_tokens = in_sizes[0];
    const int dim = out_size / n_tokens;          // 1024
    const int threads = dim / 4;                  // 256 lanes, 4 elems each

    bnb8_embed_kernel<<<n_tokens, threads, 0, stream>>>(x, qw, absmax, out, dim);
}